// Round 10
// baseline (9926.642 us; speedup 1.0000x reference)
//
#include <hip/hip_runtime.h>
#include <math.h>

#define NB   4096
#define HID  512
#define G4H  2048
#define EDIM 256
#define FINP 8
#define TSTEPS 64
#define FWIN 32

typedef __bf16 bf16;
typedef bf16  bf16x8 __attribute__((ext_vector_type(8)));
typedef float f32x4  __attribute__((ext_vector_type(4)));

__device__ __forceinline__ float sigf(float x) { return 1.0f / (1.0f + __expf(-x)); }
__device__ __forceinline__ float tanhf_(float x) { return 2.0f * sigf(2.0f * x) - 1.0f; }

__device__ __forceinline__ void gload16(const void* g, void* l) {
    __builtin_amdgcn_global_load_lds((const __attribute__((address_space(1))) void*)g,
                                     (__attribute__((address_space(3))) void*)l, 16, 0, 0);
}

// Bijective XCD-chunked swizzle (nwg % 8 == 0; gridDim.x == 32)
__device__ __forceinline__ void swz32(int& bx, int& by) {
    int nwg  = (int)(gridDim.x * gridDim.y);
    int orig = (int)(blockIdx.x + blockIdx.y * gridDim.x);
    int swz  = (orig & 7) * (nwg >> 3) + (orig >> 3);
    bx = swz & 31;
    by = swz >> 5;
}

// ---------------------------------------------------------------------------
// 128x128-tile bf16 MFMA accumulate (R8 layout: coalesced 64B-group staging
// + XOR col swizzle -> conflict-free LDS reads, SQ_LDS_BANK_CONFLICT==0).
// ---------------------------------------------------------------------------
__device__ __forceinline__ void gemm_acc(
    const bf16* __restrict__ A1, const bf16* __restrict__ W1,
    const bf16* __restrict__ A2, const bf16* __restrict__ W2, int npass,
    int m0, int n0, bf16 (&As)[2][4096], bf16 (&Ws)[2][4096], f32x4 (&acc)[4][4])
{
    const int tid  = threadIdx.x;
    const int lane = tid & 63;
    const int w    = tid >> 6;
    const int wr   = w >> 1, wc = w & 1;
    const int l16  = lane & 15;
    const int NK   = npass << 4;

    const int r0 = tid >> 2;
    const int o0 = ((tid & 3) ^ ((tid >> 3) & 3)) * 8;   // XOR col swizzle

    auto stage = [&](int s, int b) {
        const bf16* A = (s < 16) ? A1 : A2;
        const bf16* W = (s < 16) ? W1 : W2;
        const int k0 = ((s & 15) << 5) + o0;
        gload16(A + (size_t)(m0 + r0) * HID + k0,      &As[b][tid * 8]);
        gload16(A + (size_t)(m0 + r0 + 64) * HID + k0, &As[b][(tid + 256) * 8]);
        gload16(W + (size_t)(n0 + r0) * HID + k0,      &Ws[b][tid * 8]);
        gload16(W + (size_t)(n0 + r0 + 64) * HID + k0, &Ws[b][(tid + 256) * 8]);
    };

    const int swz_k = (((lane >> 4) ^ ((l16 >> 1) & 3))) * 8;
    const int aoff = wr * 2048 + l16 * 32 + swz_k;
    const int boff = wc * 2048 + l16 * 32 + swz_k;

    stage(0, 0);
    __syncthreads();
    int cur = 0;
    for (int s = 0; s < NK; ++s) {
        if (s + 1 < NK) stage(s + 1, cur ^ 1);
        const bf16* ap = &As[cur][aoff];
        const bf16* bp = &Ws[cur][boff];
        bf16x8 af[4], bfr[4];
#pragma unroll
        for (int m = 0; m < 4; ++m) af[m] = *(const bf16x8*)(ap + m * 512);
#pragma unroll
        for (int n = 0; n < 4; ++n) bfr[n] = *(const bf16x8*)(bp + n * 512);
#pragma unroll
        for (int m = 0; m < 4; ++m)
#pragma unroll
            for (int n = 0; n < 4; ++n)
                acc[m][n] = __builtin_amdgcn_mfma_f32_16x16x32_bf16(af[m], bfr[n], acc[m][n], 0, 0, 0);
        __syncthreads();
        cur ^= 1;
    }
}

// ---------------------------------------------------------------------------
// LSTM epilogue (gate-interleaved weight order; lane-local nonlinearity).
// ---------------------------------------------------------------------------
template<bool HASX>
__device__ __forceinline__ void lstm_epi(f32x4 (&acc)[4][4],
    const float* __restrict__ Wfc, const float* __restrict__ bias,
    const float* __restrict__ xA, int sx,
    float* __restrict__ cst, bf16* __restrict__ hdst, int m0, int n0)
{
    const int tid = threadIdx.x, lane = tid & 63, w = tid >> 6;
    const int wr = w >> 1, wc = w & 1, l16 = lane & 15, lq = lane >> 4;
    const int hu = (n0 >> 2) + wc * 16 + l16;
    const int jb = n0 + wc * 64 + l16;

    float bq[4];
    f32x4 wf0[4], wf1[4];
#pragma unroll
    for (int g = 0; g < 4; ++g) {
        bq[g] = bias[jb + g * 16];
        if constexpr (HASX) {
            const float* wrow = Wfc + (size_t)(jb + g * 16) * 8;
            wf0[g] = *(const f32x4*)wrow;
            wf1[g] = *(const f32x4*)(wrow + 4);
        }
    }
#pragma unroll
    for (int m = 0; m < 4; ++m) {
        const int rb = m0 + wr * 64 + m * 16 + lq * 4;
#pragma unroll
        for (int q = 0; q < 4; ++q) {
            const int r = rb + q;
            float d0 = 0.f, d1 = 0.f, d2 = 0.f, d3 = 0.f;
            if constexpr (HASX) {
                const float* xr = xA + (size_t)r * sx;
                f32x4 xv0 = *(const f32x4*)xr;
                f32x4 xv1 = *(const f32x4*)(xr + 4);
                f32x4 p0 = xv0 * wf0[0] + xv1 * wf1[0];
                f32x4 p1 = xv0 * wf0[1] + xv1 * wf1[1];
                f32x4 p2 = xv0 * wf0[2] + xv1 * wf1[2];
                f32x4 p3 = xv0 * wf0[3] + xv1 * wf1[3];
                d0 = p0[0] + p0[1] + p0[2] + p0[3];
                d1 = p1[0] + p1[1] + p1[2] + p1[3];
                d2 = p2[0] + p2[1] + p2[2] + p2[3];
                d3 = p3[0] + p3[1] + p3[2] + p3[3];
            }
            float gi = acc[m][0][q] + bq[0] + d0;
            float gf = acc[m][1][q] + bq[1] + d1;
            float gg = acc[m][2][q] + bq[2] + d2;
            float go = acc[m][3][q] + bq[3] + d3;
            float iv = sigf(gi), fv = sigf(gf), gv = tanhf_(gg), ov = sigf(go);
            size_t ci = (size_t)r * HID + hu;
            float cn = fv * cst[ci] + iv * gv;
            cst[ci] = cn;
            hdst[ci] = (bf16)(ov * tanhf_(cn));
        }
    }
}

// ---------------------------------------------------------------------------
// Per-group device-scope barrier (monotonic target; 64B-padded counters).
// ---------------------------------------------------------------------------
__device__ __forceinline__ void group_bar(unsigned* bar, int group, unsigned target) {
    __syncthreads();
    if (threadIdx.x == 0) {
        __hip_atomic_fetch_add(&bar[group * 16], 1u, __ATOMIC_RELEASE, __HIP_MEMORY_SCOPE_AGENT);
        while (__hip_atomic_load(&bar[group * 16], __ATOMIC_ACQUIRE, __HIP_MEMORY_SCOPE_AGENT) < target)
            __builtin_amdgcn_s_sleep(1);
    }
    __syncthreads();
}

// ---------------------------------------------------------------------------
// Persistent encoder, 512 blocks (cooperative): group = m-block (32 groups x
// 16 blocks). Each block per step does BOTH its L0 tile (h0[t+1]) and L1 tile
// (h1[t]) -- both depend only on barrier-(t) state. One barrier per step.
// 512 blocks = 2/CU even under a 64KB-LDS occupancy model (R9's 1024-block
// launch was likely rejected by cooperative occupancy validation).
// ---------------------------------------------------------------------------
__global__ __launch_bounds__(256)
void enc_persist2(bf16* H0a, bf16* H0b, bf16* H1a, bf16* H1b,
                  const bf16* Whh0c, const bf16* Wih1c, const bf16* Whh1c,
                  const float* Wf0c, const float* bf0c, const float* bs1c,
                  const float* x, float* c0, float* c1, unsigned* bar)
{
    __shared__ __align__(16) bf16 As[2][4096], Ws[2][4096];
    const int gid   = (int)blockIdx.x;       // 0..511
    const int group = gid >> 4;              // 0..31
    const int role  = gid & 15;              // 0..15
    const int m0    = group * 128;
    const int n0    = role * 128;
    bf16* H0[2] = {H0a, H0b};
    bf16* H1[2] = {H1a, H1b};

    f32x4 acc[4][4];
    for (int t = 0; t < TSTEPS - 2; ++t) {   // t = 0..61
        // ---- L0: h0[t+1] from h0[t] ----
#pragma unroll
        for (int m = 0; m < 4; ++m)
#pragma unroll
            for (int n = 0; n < 4; ++n) acc[m][n] = (f32x4){0.f, 0.f, 0.f, 0.f};
        gemm_acc(H0[t & 1], Whh0c, nullptr, nullptr, 1, m0, n0, As, Ws, acc);
        lstm_epi<true>(acc, Wf0c, bf0c, x + (size_t)(t + 1) * FINP, TSTEPS * FINP,
                       c0, H0[(t + 1) & 1], m0, n0);
        // ---- L1: h1[t] from h0[t], h1[t-1] ----
#pragma unroll
        for (int m = 0; m < 4; ++m)
#pragma unroll
            for (int n = 0; n < 4; ++n) acc[m][n] = (f32x4){0.f, 0.f, 0.f, 0.f};
        if (t == 0)
            gemm_acc(H0[0], Wih1c, nullptr, nullptr, 1, m0, n0, As, Ws, acc);
        else
            gemm_acc(H0[t & 1], Wih1c, H1[(t + 1) & 1], Whh1c, 2, m0, n0, As, Ws, acc);
        lstm_epi<false>(acc, nullptr, bs1c, nullptr, 0, c1, H1[t & 1], m0, n0);
        group_bar(bar, group, 16u * (t + 1));
    }
    // ---- tail: L1[62] from h0[62]=H0[0], h1[61]=H1[1] -> H1[0] ----
#pragma unroll
    for (int m = 0; m < 4; ++m)
#pragma unroll
        for (int n = 0; n < 4; ++n) acc[m][n] = (f32x4){0.f, 0.f, 0.f, 0.f};
    gemm_acc(H0[0], Wih1c, H1[1], Whh1c, 2, m0, n0, As, Ws, acc);
    lstm_epi<false>(acc, nullptr, bs1c, nullptr, 0, c1, H1[0], m0, n0);
}

// ---------------------------------------------------------------------------
// Fallback fused encoder step (R8, proven 63us): layer0[t+1] || layer1[t].
// ---------------------------------------------------------------------------
template<bool L1TWO>
__global__ __launch_bounds__(256)
void enc_fused(const bf16* __restrict__ h0_in, const bf16* __restrict__ Whh0c,
               const float* __restrict__ Wf0c, const float* __restrict__ bf0c,
               const float* __restrict__ xA,
               bf16* __restrict__ h0_out, float* __restrict__ c0,
               const bf16* __restrict__ Wih1c, const bf16* __restrict__ h1_in,
               const bf16* __restrict__ Whh1c, const float* __restrict__ bs1c,
               bf16* __restrict__ h1_out, float* __restrict__ c1)
{
    __shared__ __align__(16) bf16 As[2][4096], Ws[2][4096];
    int orig = (int)(blockIdx.x + blockIdx.y * gridDim.x);    // 0..1023
    int swz  = (orig & 7) * 128 + (orig >> 3);                // XCD-chunked
    int layer = swz & 1;
    int rest  = swz >> 1;                                     // 0..511
    const int m0 = (rest & 31) * 128;
    const int n0 = (rest >> 5) * 128;
    f32x4 acc[4][4];
#pragma unroll
    for (int m = 0; m < 4; ++m)
#pragma unroll
        for (int n = 0; n < 4; ++n) acc[m][n] = (f32x4){0.f, 0.f, 0.f, 0.f};
    if (layer == 0) {
        gemm_acc(h0_in, Whh0c, nullptr, nullptr, 1, m0, n0, As, Ws, acc);
        lstm_epi<true>(acc, Wf0c, bf0c, xA, TSTEPS * FINP, c0, h0_out, m0, n0);
    } else {
        gemm_acc(h0_in, Wih1c, h1_in, Whh1c, L1TWO ? 2 : 1, m0, n0, As, Ws, acc);
        lstm_epi<false>(acc, nullptr, bs1c, nullptr, 0, c1, h1_out, m0, n0);
    }
}

// ---------------------------------------------------------------------------
// Standalone LSTM cell (decoder + fallback-final). grid (32,16).
// ---------------------------------------------------------------------------
template<int NPASS, bool HASX>
__global__ __launch_bounds__(256)
void lstm_step(const bf16* __restrict__ A1, const bf16* __restrict__ W1,
               const bf16* __restrict__ A2, const bf16* __restrict__ W2,
               const float* __restrict__ Wfc, const float* __restrict__ bias,
               const float* __restrict__ xA, int sx,
               float* __restrict__ cst, bf16* __restrict__ hdst)
{
    __shared__ __align__(16) bf16 As[2][4096], Ws[2][4096];
    int bx, by; swz32(bx, by);
    const int m0 = bx * 128, n0 = by * 128;
    f32x4 acc[4][4];
#pragma unroll
    for (int m = 0; m < 4; ++m)
#pragma unroll
        for (int n = 0; n < 4; ++n) acc[m][n] = (f32x4){0.f, 0.f, 0.f, 0.f};
    gemm_acc(A1, W1, A2, W2, NPASS, m0, n0, As, Ws, acc);
    lstm_epi<HASX>(acc, Wfc, bias, xA, sx, cst, hdst, m0, n0);
}

// ---------------------------------------------------------------------------
// Encoder step 0 (h=0, c=0): epilogue-only. grid 8192 x 256.
// ---------------------------------------------------------------------------
__global__ __launch_bounds__(256)
void init_step(const float* __restrict__ x, const float* __restrict__ Wf0c,
               const float* __restrict__ bf0c, bf16* __restrict__ h0,
               float* __restrict__ c0)
{
    int idx = blockIdx.x * 256 + threadIdx.x;     // = r*512 + hu
    int r = idx >> 9, hu = idx & 511;
    const float* xr = x + (size_t)r * (TSTEPS * FINP);
    f32x4 xv0 = *(const f32x4*)xr;
    f32x4 xv1 = *(const f32x4*)(xr + 4);
    int jb = ((hu >> 4) << 6) + (hu & 15);
    float g[4];
#pragma unroll
    for (int gg = 0; gg < 4; ++gg) {
        const float* wrow = Wf0c + (size_t)(jb + gg * 16) * 8;
        f32x4 w0 = *(const f32x4*)wrow;
        f32x4 w1 = *(const f32x4*)(wrow + 4);
        f32x4 p = xv0 * w0 + xv1 * w1;
        g[gg] = bf0c[jb + gg * 16] + p[0] + p[1] + p[2] + p[3];
    }
    float iv = sigf(g[0]), gv = tanhf_(g[2]), ov = sigf(g[3]);
    float cn = iv * gv;                            // c_prev = 0
    c0[idx] = cn;
    h0[idx] = (bf16)(ov * tanhf_(cn));
}

// ---------------------------------------------------------------------------
// fc1: Z = A @ W^T + b (fp32 out). grid (32,4).
// ---------------------------------------------------------------------------
__global__ __launch_bounds__(256)
void fc1_mfma(const bf16* __restrict__ A, const bf16* __restrict__ W,
              const float* __restrict__ bias, float* __restrict__ Z)
{
    __shared__ __align__(16) bf16 As[2][4096], Ws[2][4096];
    int bx, by; swz32(bx, by);
    const int m0 = bx * 128, n0 = by * 128;
    f32x4 acc[4][4];
#pragma unroll
    for (int m = 0; m < 4; ++m)
#pragma unroll
        for (int n = 0; n < 4; ++n) acc[m][n] = (f32x4){0.f, 0.f, 0.f, 0.f};
    gemm_acc(A, W, nullptr, nullptr, 1, m0, n0, As, Ws, acc);

    const int tid = threadIdx.x, lane = tid & 63, w = tid >> 6;
    const int wr = w >> 1, wc = w & 1, l16 = lane & 15, lq = lane >> 4;
#pragma unroll
    for (int m = 0; m < 4; ++m) {
        const int rb = m0 + wr * 64 + m * 16 + lq * 4;
#pragma unroll
        for (int n = 0; n < 4; ++n) {
            const int col = n0 + wc * 64 + n * 16 + l16;
            float bv = bias[col];
#pragma unroll
            for (int q = 0; q < 4; ++q)
                Z[(size_t)(rb + q) * HID + col] = acc[m][n][q] + bv;
        }
    }
}

// ---------------------------------------------------------------------------
// LayerNorm + ReLU + fc2 (8 outs), one wave per row.
// ---------------------------------------------------------------------------
__global__ __launch_bounds__(256)
void ln_fc2_kernel(const float* __restrict__ Z, const float* __restrict__ lng,
                   const float* __restrict__ lnb, const float* __restrict__ w2,
                   const float* __restrict__ b2, float* __restrict__ out)
{
    int wave = threadIdx.x >> 6;
    int lane = threadIdx.x & 63;
    int n = blockIdx.x * 4 + wave;
    const float* zr = Z + (size_t)n * HID;

    float v[8];
    float s1 = 0.f, s2 = 0.f;
#pragma unroll
    for (int j = 0; j < 8; ++j) {
        v[j] = zr[lane + j * 64];
        s1 += v[j];
        s2 += v[j] * v[j];
    }
#pragma unroll
    for (int off = 32; off; off >>= 1) {
        s1 += __shfl_down(s1, off);
        s2 += __shfl_down(s2, off);
    }
    s1 = __shfl(s1, 0);
    s2 = __shfl(s2, 0);
    float mu = s1 * (1.f / 512.f);
    float var = s2 * (1.f / 512.f) - mu * mu;
    float rs = rsqrtf(var + 1e-5f);

    float y[8];
#pragma unroll
    for (int f = 0; f < 8; ++f) y[f] = 0.f;
#pragma unroll
    for (int j = 0; j < 8; ++j) {
        int h = lane + j * 64;
        float zn = (v[j] - mu) * rs * lng[h] + lnb[h];
        zn = fmaxf(zn, 0.f);
#pragma unroll
        for (int f = 0; f < 8; ++f) y[f] += zn * w2[f * HID + h];
    }
#pragma unroll
    for (int f = 0; f < 8; ++f)
#pragma unroll
        for (int off = 32; off; off >>= 1) y[f] += __shfl_down(y[f], off);

    if (lane == 0) {
#pragma unroll
        for (int f = 0; f < 8; ++f) out[(size_t)n * 256 + f] = y[f] + b2[f];
    }
}

// ---------------------------------------------------------------------------
// Weight preprocessing
// ---------------------------------------------------------------------------
__device__ __forceinline__ int remap_j(int j) {
    int gate = j >> 9, hu = j & 511;
    return ((hu >> 4) << 6) + (gate << 4) + (hu & 15);
}

__global__ void fold_small(const float* __restrict__ Wih0, const float* __restrict__ We,
                           const float* __restrict__ be, const float* __restrict__ bih0,
                           const float* __restrict__ bhh0, const float* __restrict__ bih1,
                           const float* __restrict__ bhh1,
                           float* __restrict__ Wf0c, float* __restrict__ bf0c,
                           float* __restrict__ bs1c)
{
    int j = blockIdx.x * 256 + threadIdx.x;
    if (j >= G4H) return;
    int jn = remap_j(j);
    float acc[FINP];
#pragma unroll
    for (int f = 0; f < FINP; ++f) acc[f] = 0.f;
    float bacc = 0.f;
    for (int e = 0; e < EDIM; ++e) {
        float wv = Wih0[(size_t)j * EDIM + e];
        bacc += wv * be[e];
#pragma unroll
        for (int f = 0; f < FINP; ++f) acc[f] += wv * We[e * FINP + f];
    }
#pragma unroll
    for (int f = 0; f < FINP; ++f) Wf0c[(size_t)jn * FINP + f] = acc[f];
    bf0c[jn] = bacc + bih0[j] + bhh0[j];
    bs1c[jn] = bih1[j] + bhh1[j];
}

__global__ void conv_w(const float* __restrict__ W0, const float* __restrict__ W1,
                       const float* __restrict__ W2,
                       bf16* __restrict__ O0, bf16* __restrict__ O1, bf16* __restrict__ O2)
{
    int j = blockIdx.x;
    int which = blockIdx.y;
    const float* src = which == 0 ? W0 : which == 1 ? W1 : W2;
    bf16* dst = which == 0 ? O0 : which == 1 ? O1 : O2;
    int jn = remap_j(j);
    for (int k = threadIdx.x; k < HID; k += 256)
        dst[(size_t)jn * HID + k] = (bf16)src[(size_t)j * HID + k];
}

__global__ void conv_fc1(const float* __restrict__ W, bf16* __restrict__ O)
{
    int j = blockIdx.x;
    for (int k = threadIdx.x; k < HID; k += 256)
        O[(size_t)j * HID + k] = (bf16)W[(size_t)j * HID + k];
}

// ---------------------------------------------------------------------------
extern "C" void kernel_launch(void* const* d_in, const int* in_sizes, int n_in,
                              void* d_out, int out_size, void* d_ws, size_t ws_size,
                              hipStream_t stream)
{
    const float* x    = (const float*)d_in[0];
    const float* We   = (const float*)d_in[1];
    const float* be   = (const float*)d_in[2];
    const float* Wih0 = (const float*)d_in[3];
    const float* Whh0 = (const float*)d_in[4];
    const float* bih0 = (const float*)d_in[5];
    const float* bhh0 = (const float*)d_in[6];
    const float* Wih1 = (const float*)d_in[7];
    const float* Whh1 = (const float*)d_in[8];
    const float* bih1 = (const float*)d_in[9];
    const float* bhh1 = (const float*)d_in[10];
    const float* fc1w = (const float*)d_in[11];
    const float* fc1b = (const float*)d_in[12];
    const float* lng  = (const float*)d_in[13];
    const float* lnb  = (const float*)d_in[14];
    const float* fc2w = (const float*)d_in[15];
    const float* fc2b = (const float*)d_in[16];
    float* out = (float*)d_out;

    char* p = (char*)d_ws;
    auto alloc = [&](size_t bytes) -> void* {
        void* r = (void*)p;
        p += (bytes + 255) & ~(size_t)255;
        return r;
    };
    bf16*  Whh0c = (bf16*)alloc((size_t)G4H * HID * 2);
    bf16*  Wih1c = (bf16*)alloc((size_t)G4H * HID * 2);
    bf16*  Whh1c = (bf16*)alloc((size_t)G4H * HID * 2);
    bf16*  fc1wb = (bf16*)alloc((size_t)HID * HID * 2);
    float* Wf0c  = (float*)alloc((size_t)G4H * FINP * 4);
    float* bf0c  = (float*)alloc((size_t)G4H * 4);
    float* bs1c  = (float*)alloc((size_t)G4H * 4);
    const size_t S = (size_t)NB * HID;
    bf16*  H0[2]; H0[0] = (bf16*)alloc(S * 2); H0[1] = (bf16*)alloc(S * 2);
    bf16*  H1[2]; H1[0] = (bf16*)alloc(S * 2); H1[1] = (bf16*)alloc(S * 2);
    float* c0    = (float*)alloc(S * 4);
    float* c1    = (float*)alloc(S * 4);
    float* Z     = (float*)alloc(S * 4);
    unsigned* bar = (unsigned*)alloc(32 * 64);   // 32 groups x 64B-padded ctr

    hipMemsetAsync(c1, 0, S * 4, stream);        // L1[0] epilogue reads c1=0
    hipMemsetAsync(bar, 0, 32 * 64, stream);     // reset group barriers per call

    fold_small<<<8, 256, 0, stream>>>(Wih0, We, be, bih0, bhh0, bih1, bhh1, Wf0c, bf0c, bs1c);
    conv_w<<<dim3(G4H, 3), 256, 0, stream>>>(Whh0, Wih1, Whh1, Whh0c, Wih1c, Whh1c);
    conv_fc1<<<HID, 256, 0, stream>>>(fc1w, fc1wb);

    // ----- encoder -----
    init_step<<<NB * HID / 256, 256, 0, stream>>>(x, Wf0c, bf0c, H0[0], c0);

    dim3 lb(256);
    {
        bf16 *h0a = H0[0], *h0b = H0[1], *h1a = H1[0], *h1b = H1[1];
        const float* xx = x;
        void* args[] = {&h0a, &h0b, &h1a, &h1b,
                        (void*)&Whh0c, (void*)&Wih1c, (void*)&Whh1c,
                        (void*)&Wf0c, (void*)&bf0c, (void*)&bs1c,
                        (void*)&xx, &c0, &c1, &bar};
        hipError_t cerr = hipLaunchCooperativeKernel((const void*)enc_persist2,
                                                     dim3(512), dim3(256), args, 0, stream);
        if (cerr != hipSuccess) {
            (void)hipGetLastError();   // clear sticky error, take fallback path
            dim3 fg(32, 32);
            for (int t = 0; t < TSTEPS - 2; ++t) {
                if (t == 0)
                    enc_fused<false><<<fg, lb, 0, stream>>>(H0[0], Whh0c, Wf0c, bf0c,
                        x + (size_t)1 * FINP, H0[1], c0,
                        Wih1c, nullptr, Whh1c, bs1c, H1[0], c1);
                else
                    enc_fused<true><<<fg, lb, 0, stream>>>(H0[t & 1], Whh0c, Wf0c, bf0c,
                        x + (size_t)(t + 1) * FINP, H0[(t + 1) & 1], c0,
                        Wih1c, H1[(t + 1) & 1], Whh1c, bs1c, H1[t & 1], c1);
            }
            lstm_step<2, false><<<dim3(32, 16), lb, 0, stream>>>(
                H0[0], Wih1c, H1[1], Whh1c, nullptr, bs1c, nullptr, 0, c1, H1[0]);
        }
    }
    // post-encoder state: h0[62] in H0[0], h1[62] in H1[0].

    // ----- decoder: s = 0..31 (unchanged from R8).
    for (int s = 0; s < FWIN; ++s) {
        const float* xA = (s == 0) ? (x + (size_t)(TSTEPS - 1) * FINP)
                                   : (out + (size_t)(s - 1) * FINP);
        int sx = (s == 0) ? (TSTEPS * FINP) : (FWIN * FINP);
        lstm_step<1, true><<<dim3(32, 16), lb, 0, stream>>>(
            H0[s & 1], Whh0c, nullptr, nullptr, Wf0c, bf0c, xA, sx, c0, H0[(s + 1) & 1]);
        lstm_step<2, false><<<dim3(32, 16), lb, 0, stream>>>(
            H0[(s + 1) & 1], Wih1c, H1[s & 1], Whh1c, nullptr, bs1c, nullptr, 0,
            c1, H1[(s + 1) & 1]);
        fc1_mfma<<<dim3(32, 4), lb, 0, stream>>>(H1[(s + 1) & 1], fc1wb, fc1b, Z);
        ln_fc2_kernel<<<NB / 4, 256, 0, stream>>>(Z, lng, lnb, fc2w, fc2b,
                                                  out + (size_t)s * FINP);
    }
}

// Round 11
// 6265.555 us; speedup vs baseline: 1.5843x; 1.5843x over previous
//
#include <hip/hip_runtime.h>
#include <math.h>

#define NB   4096
#define HID  512
#define G4H  2048
#define EDIM 256
#define FINP 8
#define TSTEPS 64
#define FWIN 32

typedef __bf16 bf16;
typedef bf16  bf16x8 __attribute__((ext_vector_type(8)));
typedef float f32x4  __attribute__((ext_vector_type(4)));

__device__ __forceinline__ float sigf(float x) { return 1.0f / (1.0f + __expf(-x)); }
__device__ __forceinline__ float tanhf_(float x) { return 2.0f * sigf(2.0f * x) - 1.0f; }

__device__ __forceinline__ void gload16(const void* g, void* l) {
    __builtin_amdgcn_global_load_lds((const __attribute__((address_space(1))) void*)g,
                                     (__attribute__((address_space(3))) void*)l, 16, 0, 0);
}

// Bijective XCD-chunked swizzle (nwg % 8 == 0; gridDim.x == 32)
__device__ __forceinline__ void swz32(int& bx, int& by) {
    int nwg  = (int)(gridDim.x * gridDim.y);
    int orig = (int)(blockIdx.x + blockIdx.y * gridDim.x);
    int swz  = (orig & 7) * (nwg >> 3) + (orig >> 3);
    bx = swz & 31;
    by = swz >> 5;
}

// ---------------------------------------------------------------------------
// 128x128-tile bf16 MFMA accumulate over npass*512 K.
// R8 LDS chunk layout (coalesced 64B-group staging + XOR col swizzle ->
// conflict-free reads, SQ_LDS_BANK_CONFLICT==0 measured).
// NEW (R11): 3-buffer, 2-tile-deep pipeline with counted vmcnt (T3/T4):
//   prologue: stage(0,b0), stage(1,b1), vmcnt(4)          [tile0 landed]
//   iter s:   barrier; stage(s+2 -> (s+2)%3); ds_read+MFMA(s%3);
//             vmcnt(4)  (tail: vmcnt(0))
// Ledger: <=8 loads in flight; vmcnt(4) at iter s retires tile s+1's loads;
// buffer (s+2)%3 was last read at iter s-1 and the top barrier proves all
// waves done with it. One barrier/iter; loads get ~2 compute phases to land
// (R6's failed variant had ZERO depth + an extra barrier -- different regime).
// 256 threads = 4 waves (2x2 of 64x64). A,W row-major ld=512.
// ---------------------------------------------------------------------------
__device__ __forceinline__ void gemm_acc(
    const bf16* __restrict__ A1, const bf16* __restrict__ W1,
    const bf16* __restrict__ A2, const bf16* __restrict__ W2, int npass,
    int m0, int n0, bf16 (&As)[3][4096], bf16 (&Ws)[3][4096], f32x4 (&acc)[4][4])
{
    const int tid  = threadIdx.x;
    const int lane = tid & 63;
    const int w    = tid >> 6;
    const int wr   = w >> 1, wc = w & 1;
    const int l16  = lane & 15;
    const int NK   = npass << 4;

    const int r0 = tid >> 2;
    const int o0 = ((tid & 3) ^ ((tid >> 3) & 3)) * 8;   // XOR col swizzle

    auto stage = [&](int s, int b) {
        const bf16* A = (s < 16) ? A1 : A2;
        const bf16* W = (s < 16) ? W1 : W2;
        const int k0 = ((s & 15) << 5) + o0;
        gload16(A + (size_t)(m0 + r0) * HID + k0,      &As[b][tid * 8]);
        gload16(A + (size_t)(m0 + r0 + 64) * HID + k0, &As[b][(tid + 256) * 8]);
        gload16(W + (size_t)(n0 + r0) * HID + k0,      &Ws[b][tid * 8]);
        gload16(W + (size_t)(n0 + r0 + 64) * HID + k0, &Ws[b][(tid + 256) * 8]);
    };

    const int swz_k = (((lane >> 4) ^ ((l16 >> 1) & 3))) * 8;
    const int aoff = wr * 2048 + l16 * 32 + swz_k;
    const int boff = wc * 2048 + l16 * 32 + swz_k;

    stage(0, 0);
    stage(1, 1);
    asm volatile("s_waitcnt vmcnt(4)" ::: "memory");     // tile 0 landed
    int cur = 0;
    for (int s = 0; s < NK; ++s) {
        __builtin_amdgcn_s_barrier();                    // peers' tile-s loads done;
                                                         // buf (s+2)%3 free to overwrite
        if (s + 2 < NK) {
            int nb = cur + 2; if (nb >= 3) nb -= 3;
            stage(s + 2, nb);                            // 2-deep prefetch
        }
        const bf16* ap = &As[cur][aoff];
        const bf16* bp = &Ws[cur][boff];
        bf16x8 af[4], bfr[4];
#pragma unroll
        for (int m = 0; m < 4; ++m) af[m] = *(const bf16x8*)(ap + m * 512);
#pragma unroll
        for (int n = 0; n < 4; ++n) bfr[n] = *(const bf16x8*)(bp + n * 512);
#pragma unroll
        for (int m = 0; m < 4; ++m)
#pragma unroll
            for (int n = 0; n < 4; ++n)
                acc[m][n] = __builtin_amdgcn_mfma_f32_16x16x32_bf16(af[m], bfr[n], acc[m][n], 0, 0, 0);
        if (s + 2 < NK)
            asm volatile("s_waitcnt vmcnt(4)" ::: "memory");   // tile s+1 landed
        else if (s + 1 < NK)
            asm volatile("s_waitcnt vmcnt(0)" ::: "memory");   // final tile landed
        cur = (cur + 1 == 3) ? 0 : cur + 1;
    }
}

// ---------------------------------------------------------------------------
// LSTM epilogue (gate-interleaved weight order; lane-local nonlinearity).
// ---------------------------------------------------------------------------
template<bool HASX>
__device__ __forceinline__ void lstm_epi(f32x4 (&acc)[4][4],
    const float* __restrict__ Wfc, const float* __restrict__ bias,
    const float* __restrict__ xA, int sx,
    float* __restrict__ cst, bf16* __restrict__ hdst, int m0, int n0)
{
    const int tid = threadIdx.x, lane = tid & 63, w = tid >> 6;
    const int wr = w >> 1, wc = w & 1, l16 = lane & 15, lq = lane >> 4;
    const int hu = (n0 >> 2) + wc * 16 + l16;
    const int jb = n0 + wc * 64 + l16;

    float bq[4];
    f32x4 wf0[4], wf1[4];
#pragma unroll
    for (int g = 0; g < 4; ++g) {
        bq[g] = bias[jb + g * 16];
        if constexpr (HASX) {
            const float* wrow = Wfc + (size_t)(jb + g * 16) * 8;
            wf0[g] = *(const f32x4*)wrow;
            wf1[g] = *(const f32x4*)(wrow + 4);
        }
    }
#pragma unroll
    for (int m = 0; m < 4; ++m) {
        const int rb = m0 + wr * 64 + m * 16 + lq * 4;
#pragma unroll
        for (int q = 0; q < 4; ++q) {
            const int r = rb + q;
            float d0 = 0.f, d1 = 0.f, d2 = 0.f, d3 = 0.f;
            if constexpr (HASX) {
                const float* xr = xA + (size_t)r * sx;
                f32x4 xv0 = *(const f32x4*)xr;
                f32x4 xv1 = *(const f32x4*)(xr + 4);
                f32x4 p0 = xv0 * wf0[0] + xv1 * wf1[0];
                f32x4 p1 = xv0 * wf0[1] + xv1 * wf1[1];
                f32x4 p2 = xv0 * wf0[2] + xv1 * wf1[2];
                f32x4 p3 = xv0 * wf0[3] + xv1 * wf1[3];
                d0 = p0[0] + p0[1] + p0[2] + p0[3];
                d1 = p1[0] + p1[1] + p1[2] + p1[3];
                d2 = p2[0] + p2[1] + p2[2] + p2[3];
                d3 = p3[0] + p3[1] + p3[2] + p3[3];
            }
            float gi = acc[m][0][q] + bq[0] + d0;
            float gf = acc[m][1][q] + bq[1] + d1;
            float gg = acc[m][2][q] + bq[2] + d2;
            float go = acc[m][3][q] + bq[3] + d3;
            float iv = sigf(gi), fv = sigf(gf), gv = tanhf_(gg), ov = sigf(go);
            size_t ci = (size_t)r * HID + hu;
            float cn = fv * cst[ci] + iv * gv;
            cst[ci] = cn;
            hdst[ci] = (bf16)(ov * tanhf_(cn));
        }
    }
}

// ---------------------------------------------------------------------------
// Standalone LSTM cell (decoder + encoder-final). grid (32,16).
// ---------------------------------------------------------------------------
template<int NPASS, bool HASX>
__global__ __launch_bounds__(256)
void lstm_step(const bf16* __restrict__ A1, const bf16* __restrict__ W1,
               const bf16* __restrict__ A2, const bf16* __restrict__ W2,
               const float* __restrict__ Wfc, const float* __restrict__ bias,
               const float* __restrict__ xA, int sx,
               float* __restrict__ cst, bf16* __restrict__ hdst)
{
    __shared__ __align__(16) bf16 As[3][4096], Ws[3][4096];
    int bx, by; swz32(bx, by);
    const int m0 = bx * 128, n0 = by * 128;
    f32x4 acc[4][4];
#pragma unroll
    for (int m = 0; m < 4; ++m)
#pragma unroll
        for (int n = 0; n < 4; ++n) acc[m][n] = (f32x4){0.f, 0.f, 0.f, 0.f};
    gemm_acc(A1, W1, A2, W2, NPASS, m0, n0, As, Ws, acc);
    lstm_epi<HASX>(acc, Wfc, bias, xA, sx, cst, hdst, m0, n0);
}

// ---------------------------------------------------------------------------
// Fused encoder step (R8, balanced layer=swz&1 mapping): layer0[t+1]||layer1[t]
// grid (32,32).
// ---------------------------------------------------------------------------
template<bool L1TWO>
__global__ __launch_bounds__(256)
void enc_fused(const bf16* __restrict__ h0_in, const bf16* __restrict__ Whh0c,
               const float* __restrict__ Wf0c, const float* __restrict__ bf0c,
               const float* __restrict__ xA,
               bf16* __restrict__ h0_out, float* __restrict__ c0,
               const bf16* __restrict__ Wih1c, const bf16* __restrict__ h1_in,
               const bf16* __restrict__ Whh1c, const float* __restrict__ bs1c,
               bf16* __restrict__ h1_out, float* __restrict__ c1)
{
    __shared__ __align__(16) bf16 As[3][4096], Ws[3][4096];
    int orig = (int)(blockIdx.x + blockIdx.y * gridDim.x);    // 0..1023
    int swz  = (orig & 7) * 128 + (orig >> 3);                // XCD-chunked
    int layer = swz & 1;
    int rest  = swz >> 1;                                     // 0..511
    const int m0 = (rest & 31) * 128;
    const int n0 = (rest >> 5) * 128;
    f32x4 acc[4][4];
#pragma unroll
    for (int m = 0; m < 4; ++m)
#pragma unroll
        for (int n = 0; n < 4; ++n) acc[m][n] = (f32x4){0.f, 0.f, 0.f, 0.f};
    if (layer == 0) {
        gemm_acc(h0_in, Whh0c, nullptr, nullptr, 1, m0, n0, As, Ws, acc);
        lstm_epi<true>(acc, Wf0c, bf0c, xA, TSTEPS * FINP, c0, h0_out, m0, n0);
    } else {
        gemm_acc(h0_in, Wih1c, h1_in, Whh1c, L1TWO ? 2 : 1, m0, n0, As, Ws, acc);
        lstm_epi<false>(acc, nullptr, bs1c, nullptr, 0, c1, h1_out, m0, n0);
    }
}

// ---------------------------------------------------------------------------
// Encoder step 0 (h=0, c=0): epilogue-only. grid 8192 x 256.
// ---------------------------------------------------------------------------
__global__ __launch_bounds__(256)
void init_step(const float* __restrict__ x, const float* __restrict__ Wf0c,
               const float* __restrict__ bf0c, bf16* __restrict__ h0,
               float* __restrict__ c0)
{
    int idx = blockIdx.x * 256 + threadIdx.x;     // = r*512 + hu
    int r = idx >> 9, hu = idx & 511;
    const float* xr = x + (size_t)r * (TSTEPS * FINP);
    f32x4 xv0 = *(const f32x4*)xr;
    f32x4 xv1 = *(const f32x4*)(xr + 4);
    int jb = ((hu >> 4) << 6) + (hu & 15);
    float g[4];
#pragma unroll
    for (int gg = 0; gg < 4; ++gg) {
        const float* wrow = Wf0c + (size_t)(jb + gg * 16) * 8;
        f32x4 w0 = *(const f32x4*)wrow;
        f32x4 w1 = *(const f32x4*)(wrow + 4);
        f32x4 p = xv0 * w0 + xv1 * w1;
        g[gg] = bf0c[jb + gg * 16] + p[0] + p[1] + p[2] + p[3];
    }
    float iv = sigf(g[0]), gv = tanhf_(g[2]), ov = sigf(g[3]);
    float cn = iv * gv;                            // c_prev = 0
    c0[idx] = cn;
    h0[idx] = (bf16)(ov * tanhf_(cn));
}

// ---------------------------------------------------------------------------
// fc1: Z = A @ W^T + b (fp32 out). grid (32,4).
// ---------------------------------------------------------------------------
__global__ __launch_bounds__(256)
void fc1_mfma(const bf16* __restrict__ A, const bf16* __restrict__ W,
              const float* __restrict__ bias, float* __restrict__ Z)
{
    __shared__ __align__(16) bf16 As[3][4096], Ws[3][4096];
    int bx, by; swz32(bx, by);
    const int m0 = bx * 128, n0 = by * 128;
    f32x4 acc[4][4];
#pragma unroll
    for (int m = 0; m < 4; ++m)
#pragma unroll
        for (int n = 0; n < 4; ++n) acc[m][n] = (f32x4){0.f, 0.f, 0.f, 0.f};
    gemm_acc(A, W, nullptr, nullptr, 1, m0, n0, As, Ws, acc);

    const int tid = threadIdx.x, lane = tid & 63, w = tid >> 6;
    const int wr = w >> 1, wc = w & 1, l16 = lane & 15, lq = lane >> 4;
#pragma unroll
    for (int m = 0; m < 4; ++m) {
        const int rb = m0 + wr * 64 + m * 16 + lq * 4;
#pragma unroll
        for (int n = 0; n < 4; ++n) {
            const int col = n0 + wc * 64 + n * 16 + l16;
            float bv = bias[col];
#pragma unroll
            for (int q = 0; q < 4; ++q)
                Z[(size_t)(rb + q) * HID + col] = acc[m][n][q] + bv;
        }
    }
}

// ---------------------------------------------------------------------------
// LayerNorm + ReLU + fc2 (8 outs), one wave per row.
// ---------------------------------------------------------------------------
__global__ __launch_bounds__(256)
void ln_fc2_kernel(const float* __restrict__ Z, const float* __restrict__ lng,
                   const float* __restrict__ lnb, const float* __restrict__ w2,
                   const float* __restrict__ b2, float* __restrict__ out)
{
    int wave = threadIdx.x >> 6;
    int lane = threadIdx.x & 63;
    int n = blockIdx.x * 4 + wave;
    const float* zr = Z + (size_t)n * HID;

    float v[8];
    float s1 = 0.f, s2 = 0.f;
#pragma unroll
    for (int j = 0; j < 8; ++j) {
        v[j] = zr[lane + j * 64];
        s1 += v[j];
        s2 += v[j] * v[j];
    }
#pragma unroll
    for (int off = 32; off; off >>= 1) {
        s1 += __shfl_down(s1, off);
        s2 += __shfl_down(s2, off);
    }
    s1 = __shfl(s1, 0);
    s2 = __shfl(s2, 0);
    float mu = s1 * (1.f / 512.f);
    float var = s2 * (1.f / 512.f) - mu * mu;
    float rs = rsqrtf(var + 1e-5f);

    float y[8];
#pragma unroll
    for (int f = 0; f < 8; ++f) y[f] = 0.f;
#pragma unroll
    for (int j = 0; j < 8; ++j) {
        int h = lane + j * 64;
        float zn = (v[j] - mu) * rs * lng[h] + lnb[h];
        zn = fmaxf(zn, 0.f);
#pragma unroll
        for (int f = 0; f < 8; ++f) y[f] += zn * w2[f * HID + h];
    }
#pragma unroll
    for (int f = 0; f < 8; ++f)
#pragma unroll
        for (int off = 32; off; off >>= 1) y[f] += __shfl_down(y[f], off);

    if (lane == 0) {
#pragma unroll
        for (int f = 0; f < 8; ++f) out[(size_t)n * 256 + f] = y[f] + b2[f];
    }
}

// ---------------------------------------------------------------------------
// Weight preprocessing
// ---------------------------------------------------------------------------
__device__ __forceinline__ int remap_j(int j) {
    int gate = j >> 9, hu = j & 511;
    return ((hu >> 4) << 6) + (gate << 4) + (hu & 15);
}

__global__ void fold_small(const float* __restrict__ Wih0, const float* __restrict__ We,
                           const float* __restrict__ be, const float* __restrict__ bih0,
                           const float* __restrict__ bhh0, const float* __restrict__ bih1,
                           const float* __restrict__ bhh1,
                           float* __restrict__ Wf0c, float* __restrict__ bf0c,
                           float* __restrict__ bs1c)
{
    int j = blockIdx.x * 256 + threadIdx.x;
    if (j >= G4H) return;
    int jn = remap_j(j);
    float acc[FINP];
#pragma unroll
    for (int f = 0; f < FINP; ++f) acc[f] = 0.f;
    float bacc = 0.f;
    for (int e = 0; e < EDIM; ++e) {
        float wv = Wih0[(size_t)j * EDIM + e];
        bacc += wv * be[e];
#pragma unroll
        for (int f = 0; f < FINP; ++f) acc[f] += wv * We[e * FINP + f];
    }
#pragma unroll
    for (int f = 0; f < FINP; ++f) Wf0c[(size_t)jn * FINP + f] = acc[f];
    bf0c[jn] = bacc + bih0[j] + bhh0[j];
    bs1c[jn] = bih1[j] + bhh1[j];
}

__global__ void conv_w(const float* __restrict__ W0, const float* __restrict__ W1,
                       const float* __restrict__ W2,
                       bf16* __restrict__ O0, bf16* __restrict__ O1, bf16* __restrict__ O2)
{
    int j = blockIdx.x;
    int which = blockIdx.y;
    const float* src = which == 0 ? W0 : which == 1 ? W1 : W2;
    bf16* dst = which == 0 ? O0 : which == 1 ? O1 : O2;
    int jn = remap_j(j);
    for (int k = threadIdx.x; k < HID; k += 256)
        dst[(size_t)jn * HID + k] = (bf16)src[(size_t)j * HID + k];
}

__global__ void conv_fc1(const float* __restrict__ W, bf16* __restrict__ O)
{
    int j = blockIdx.x;
    for (int k = threadIdx.x; k < HID; k += 256)
        O[(size_t)j * HID + k] = (bf16)W[(size_t)j * HID + k];
}

// ---------------------------------------------------------------------------
extern "C" void kernel_launch(void* const* d_in, const int* in_sizes, int n_in,
                              void* d_out, int out_size, void* d_ws, size_t ws_size,
                              hipStream_t stream)
{
    const float* x    = (const float*)d_in[0];
    const float* We   = (const float*)d_in[1];
    const float* be   = (const float*)d_in[2];
    const float* Wih0 = (const float*)d_in[3];
    const float* Whh0 = (const float*)d_in[4];
    const float* bih0 = (const float*)d_in[5];
    const float* bhh0 = (const float*)d_in[6];
    const float* Wih1 = (const float*)d_in[7];
    const float* Whh1 = (const float*)d_in[8];
    const float* bih1 = (const float*)d_in[9];
    const float* bhh1 = (const float*)d_in[10];
    const float* fc1w = (const float*)d_in[11];
    const float* fc1b = (const float*)d_in[12];
    const float* lng  = (const float*)d_in[13];
    const float* lnb  = (const float*)d_in[14];
    const float* fc2w = (const float*)d_in[15];
    const float* fc2b = (const float*)d_in[16];
    float* out = (float*)d_out;

    char* p = (char*)d_ws;
    auto alloc = [&](size_t bytes) -> void* {
        void* r = (void*)p;
        p += (bytes + 255) & ~(size_t)255;
        return r;
    };
    bf16*  Whh0c = (bf16*)alloc((size_t)G4H * HID * 2);
    bf16*  Wih1c = (bf16*)alloc((size_t)G4H * HID * 2);
    bf16*  Whh1c = (bf16*)alloc((size_t)G4H * HID * 2);
    bf16*  fc1wb = (bf16*)alloc((size_t)HID * HID * 2);
    float* Wf0c  = (float*)alloc((size_t)G4H * FINP * 4);
    float* bf0c  = (float*)alloc((size_t)G4H * 4);
    float* bs1c  = (float*)alloc((size_t)G4H * 4);
    const size_t S = (size_t)NB * HID;
    bf16*  H0[2]; H0[0] = (bf16*)alloc(S * 2); H0[1] = (bf16*)alloc(S * 2);
    bf16*  H1[2]; H1[0] = (bf16*)alloc(S * 2); H1[1] = (bf16*)alloc(S * 2);
    float* c0    = (float*)alloc(S * 4);
    float* c1    = (float*)alloc(S * 4);
    float* Z     = (float*)alloc(S * 4);

    hipMemsetAsync(c1, 0, S * 4, stream);   // layer1[0] epilogue reads c1

    fold_small<<<8, 256, 0, stream>>>(Wih0, We, be, bih0, bhh0, bih1, bhh1, Wf0c, bf0c, bs1c);
    conv_w<<<dim3(G4H, 3), 256, 0, stream>>>(Whh0, Wih1, Whh1, Whh0c, Wih1c, Whh1c);
    conv_fc1<<<HID, 256, 0, stream>>>(fc1w, fc1wb);

    // ----- encoder: t = 0..62 (63 steps). h0[t] in H0[t&1], h1[t] in H1[t&1].
    init_step<<<NB * HID / 256, 256, 0, stream>>>(x, Wf0c, bf0c, H0[0], c0);

    dim3 fg(32, 32), lb(256);
    for (int t = 0; t < TSTEPS - 2; ++t) {   // t = 0..61: layer0[t+1] || layer1[t]
        if (t == 0)
            enc_fused<false><<<fg, lb, 0, stream>>>(H0[0], Whh0c, Wf0c, bf0c,
                x + (size_t)1 * FINP, H0[1], c0,
                Wih1c, nullptr, Whh1c, bs1c, H1[0], c1);
        else
            enc_fused<true><<<fg, lb, 0, stream>>>(H0[t & 1], Whh0c, Wf0c, bf0c,
                x + (size_t)(t + 1) * FINP, H0[(t + 1) & 1], c0,
                Wih1c, H1[(t + 1) & 1], Whh1c, bs1c, H1[t & 1], c1);
    }
    // final layer1[62]: reads h0[62]=H0[0], h1[61]=H1[1], writes H1[0]
    lstm_step<2, false><<<dim3(32, 16), lb, 0, stream>>>(
        H0[0], Wih1c, H1[1], Whh1c, nullptr, bs1c, nullptr, 0, c1, H1[0]);

    // ----- decoder: s = 0..31.
    for (int s = 0; s < FWIN; ++s) {
        const float* xA = (s == 0) ? (x + (size_t)(TSTEPS - 1) * FINP)
                                   : (out + (size_t)(s - 1) * FINP);
        int sx = (s == 0) ? (TSTEPS * FINP) : (FWIN * FINP);
        lstm_step<1, true><<<dim3(32, 16), lb, 0, stream>>>(
            H0[s & 1], Whh0c, nullptr, nullptr, Wf0c, bf0c, xA, sx, c0, H0[(s + 1) & 1]);
        lstm_step<2, false><<<dim3(32, 16), lb, 0, stream>>>(
            H0[(s + 1) & 1], Wih1c, H1[s & 1], Whh1c, nullptr, bs1c, nullptr, 0,
            c1, H1[(s + 1) & 1]);
        fc1_mfma<<<dim3(32, 4), lb, 0, stream>>>(H1[(s + 1) & 1], fc1wb, fc1b, Z);
        ln_fc2_kernel<<<NB / 4, 256, 0, stream>>>(Z, lng, lnb, fc2w, fc2b,
                                                  out + (size_t)s * FINP);
    }
}

// Round 12
// 5859.646 us; speedup vs baseline: 1.6941x; 1.0693x over previous
//
#include <hip/hip_runtime.h>
#include <math.h>

#define NB   4096
#define HID  512
#define G4H  2048
#define EDIM 256
#define FINP 8
#define TSTEPS 64
#define FWIN 32

typedef __bf16 bf16;
typedef bf16  bf16x8 __attribute__((ext_vector_type(8)));
typedef float f32x4  __attribute__((ext_vector_type(4)));

__device__ __forceinline__ float sigf(float x) { return 1.0f / (1.0f + __expf(-x)); }
__device__ __forceinline__ float tanhf_(float x) { return 2.0f * sigf(2.0f * x) - 1.0f; }

__device__ __forceinline__ void gload16(const void* g, void* l) {
    __builtin_amdgcn_global_load_lds((const __attribute__((address_space(1))) void*)g,
                                     (__attribute__((address_space(3))) void*)l, 16, 0, 0);
}

// ---------------------------------------------------------------------------
// 128x128-tile bf16 MFMA accumulate (R8 engine, proven 63us/0-conflict):
// coalesced 64B-group staging + XOR col swizzle; 2-buffer, 1 barrier/iter.
// ---------------------------------------------------------------------------
__device__ __forceinline__ void gemm_acc(
    const bf16* __restrict__ A1, const bf16* __restrict__ W1,
    const bf16* __restrict__ A2, const bf16* __restrict__ W2, int npass,
    int m0, int n0, bf16 (&As)[2][4096], bf16 (&Ws)[2][4096], f32x4 (&acc)[4][4])
{
    const int tid  = threadIdx.x;
    const int lane = tid & 63;
    const int w    = tid >> 6;
    const int wr   = w >> 1, wc = w & 1;
    const int l16  = lane & 15;
    const int NK   = npass << 4;

    const int r0 = tid >> 2;
    const int o0 = ((tid & 3) ^ ((tid >> 3) & 3)) * 8;   // XOR col swizzle

    auto stage = [&](int s, int b) {
        const bf16* A = (s < 16) ? A1 : A2;
        const bf16* W = (s < 16) ? W1 : W2;
        const int k0 = ((s & 15) << 5) + o0;
        gload16(A + (size_t)(m0 + r0) * HID + k0,      &As[b][tid * 8]);
        gload16(A + (size_t)(m0 + r0 + 64) * HID + k0, &As[b][(tid + 256) * 8]);
        gload16(W + (size_t)(n0 + r0) * HID + k0,      &Ws[b][tid * 8]);
        gload16(W + (size_t)(n0 + r0 + 64) * HID + k0, &Ws[b][(tid + 256) * 8]);
    };

    const int swz_k = (((lane >> 4) ^ ((l16 >> 1) & 3))) * 8;
    const int aoff = wr * 2048 + l16 * 32 + swz_k;
    const int boff = wc * 2048 + l16 * 32 + swz_k;

    stage(0, 0);
    __syncthreads();
    int cur = 0;
    for (int s = 0; s < NK; ++s) {
        if (s + 1 < NK) stage(s + 1, cur ^ 1);
        const bf16* ap = &As[cur][aoff];
        const bf16* bp = &Ws[cur][boff];
        bf16x8 af[4], bfr[4];
#pragma unroll
        for (int m = 0; m < 4; ++m) af[m] = *(const bf16x8*)(ap + m * 512);
#pragma unroll
        for (int n = 0; n < 4; ++n) bfr[n] = *(const bf16x8*)(bp + n * 512);
#pragma unroll
        for (int m = 0; m < 4; ++m)
#pragma unroll
            for (int n = 0; n < 4; ++n)
                acc[m][n] = __builtin_amdgcn_mfma_f32_16x16x32_bf16(af[m], bfr[n], acc[m][n], 0, 0, 0);
        __syncthreads();
        cur ^= 1;
    }
}

// ---------------------------------------------------------------------------
// LSTM epilogue (gate-interleaved weight order; lane-local nonlinearity).
// ---------------------------------------------------------------------------
template<bool HASX>
__device__ __forceinline__ void lstm_epi(f32x4 (&acc)[4][4],
    const float* __restrict__ Wfc, const float* __restrict__ bias,
    const float* __restrict__ xA, int sx,
    float* __restrict__ cst, bf16* __restrict__ hdst, int m0, int n0)
{
    const int tid = threadIdx.x, lane = tid & 63, w = tid >> 6;
    const int wr = w >> 1, wc = w & 1, l16 = lane & 15, lq = lane >> 4;
    const int hu = (n0 >> 2) + wc * 16 + l16;
    const int jb = n0 + wc * 64 + l16;

    float bq[4];
    f32x4 wf0[4], wf1[4];
#pragma unroll
    for (int g = 0; g < 4; ++g) {
        bq[g] = bias[jb + g * 16];
        if constexpr (HASX) {
            const float* wrow = Wfc + (size_t)(jb + g * 16) * 8;
            wf0[g] = *(const f32x4*)wrow;
            wf1[g] = *(const f32x4*)(wrow + 4);
        }
    }
#pragma unroll
    for (int m = 0; m < 4; ++m) {
        const int rb = m0 + wr * 64 + m * 16 + lq * 4;
#pragma unroll
        for (int q = 0; q < 4; ++q) {
            const int r = rb + q;
            float d0 = 0.f, d1 = 0.f, d2 = 0.f, d3 = 0.f;
            if constexpr (HASX) {
                const float* xr = xA + (size_t)r * sx;
                f32x4 xv0 = *(const f32x4*)xr;
                f32x4 xv1 = *(const f32x4*)(xr + 4);
                f32x4 p0 = xv0 * wf0[0] + xv1 * wf1[0];
                f32x4 p1 = xv0 * wf0[1] + xv1 * wf1[1];
                f32x4 p2 = xv0 * wf0[2] + xv1 * wf1[2];
                f32x4 p3 = xv0 * wf0[3] + xv1 * wf1[3];
                d0 = p0[0] + p0[1] + p0[2] + p0[3];
                d1 = p1[0] + p1[1] + p1[2] + p1[3];
                d2 = p2[0] + p2[1] + p2[2] + p2[3];
                d3 = p3[0] + p3[1] + p3[2] + p3[3];
            }
            float gi = acc[m][0][q] + bq[0] + d0;
            float gf = acc[m][1][q] + bq[1] + d1;
            float gg = acc[m][2][q] + bq[2] + d2;
            float go = acc[m][3][q] + bq[3] + d3;
            float iv = sigf(gi), fv = sigf(gf), gv = tanhf_(gg), ov = sigf(go);
            size_t ci = (size_t)r * HID + hu;
            float cn = fv * cst[ci] + iv * gv;
            cst[ci] = cn;
            hdst[ci] = (bf16)(ov * tanhf_(cn));
        }
    }
}

// ---------------------------------------------------------------------------
// Standalone LSTM cell (decoder + encoder-final). grid (32,16) = 512 blocks.
// 2-D XCD tiling: XCD x = orig&7 owns m-quad (x>>1: 8 m-groups -> A-slice
// 1-2MB) x n-half (x&1: 8 n-tiles -> W-slice 1-2MB); both fit the 4MB L2.
// (Old chunked swizzle gave each XCD ALL of A = 8MB -> L2 thrash,
//  FETCH 65MB vs 30MB ideal -> 900cyc A-loads -> MfmaUtil 15%.)
// ---------------------------------------------------------------------------
template<int NPASS, bool HASX>
__global__ __launch_bounds__(256)
void lstm_step(const bf16* __restrict__ A1, const bf16* __restrict__ W1,
               const bf16* __restrict__ A2, const bf16* __restrict__ W2,
               const float* __restrict__ Wfc, const float* __restrict__ bias,
               const float* __restrict__ xA, int sx,
               float* __restrict__ cst, bf16* __restrict__ hdst)
{
    __shared__ __align__(16) bf16 As[2][4096], Ws[2][4096];
    int orig = (int)(blockIdx.x + blockIdx.y * gridDim.x);   // 0..511
    int xcd = orig & 7, idx = orig >> 3;                     // idx 0..63
    int mq = xcd >> 1, nh = xcd & 1;
    int mi = idx & 7, ni = idx >> 3;                         // ni 0..7
    const int m0 = (mq * 8 + mi) * 128;
    const int n0 = (nh * 8 + ni) * 128;
    f32x4 acc[4][4];
#pragma unroll
    for (int m = 0; m < 4; ++m)
#pragma unroll
        for (int n = 0; n < 4; ++n) acc[m][n] = (f32x4){0.f, 0.f, 0.f, 0.f};
    gemm_acc(A1, W1, A2, W2, NPASS, m0, n0, As, Ws, acc);
    lstm_epi<HASX>(acc, Wfc, bias, xA, sx, cst, hdst, m0, n0);
}

// ---------------------------------------------------------------------------
// Fused encoder step: layer0[t+1] || layer1[t], grid (32,32) = 1024 blocks.
// 2-D XCD tiling with layer-interleaved columns: c = nh*16 + ni (0..31),
// layer = c&1 (balanced within XCD), n0 = (c>>1)*128.
// Per-XCD resident: A 2MB (h0+h1 m-slice) + W 3MB (16 layer-cols) ~ L2.
// ---------------------------------------------------------------------------
template<bool L1TWO>
__global__ __launch_bounds__(256)
void enc_fused(const bf16* __restrict__ h0_in, const bf16* __restrict__ Whh0c,
               const float* __restrict__ Wf0c, const float* __restrict__ bf0c,
               const float* __restrict__ xA,
               bf16* __restrict__ h0_out, float* __restrict__ c0,
               const bf16* __restrict__ Wih1c, const bf16* __restrict__ h1_in,
               const bf16* __restrict__ Whh1c, const float* __restrict__ bs1c,
               bf16* __restrict__ h1_out, float* __restrict__ c1)
{
    __shared__ __align__(16) bf16 As[2][4096], Ws[2][4096];
    int orig = (int)(blockIdx.x + blockIdx.y * gridDim.x);   // 0..1023
    int xcd = orig & 7, idx = orig >> 3;                     // idx 0..127
    int mq = xcd >> 1, nh = xcd & 1;
    int mi = idx & 7, ni = idx >> 3;                         // ni 0..15
    const int m0 = (mq * 8 + mi) * 128;
    const int c  = nh * 16 + ni;                             // 0..31
    const int layer = c & 1;
    const int n0 = (c >> 1) * 128;
    f32x4 acc[4][4];
#pragma unroll
    for (int m = 0; m < 4; ++m)
#pragma unroll
        for (int n = 0; n < 4; ++n) acc[m][n] = (f32x4){0.f, 0.f, 0.f, 0.f};
    if (layer == 0) {
        gemm_acc(h0_in, Whh0c, nullptr, nullptr, 1, m0, n0, As, Ws, acc);
        lstm_epi<true>(acc, Wf0c, bf0c, xA, TSTEPS * FINP, c0, h0_out, m0, n0);
    } else {
        gemm_acc(h0_in, Wih1c, h1_in, Whh1c, L1TWO ? 2 : 1, m0, n0, As, Ws, acc);
        lstm_epi<false>(acc, nullptr, bs1c, nullptr, 0, c1, h1_out, m0, n0);
    }
}

// ---------------------------------------------------------------------------
// Encoder step 0 (h=0, c=0): epilogue-only. grid 8192 x 256.
// ---------------------------------------------------------------------------
__global__ __launch_bounds__(256)
void init_step(const float* __restrict__ x, const float* __restrict__ Wf0c,
               const float* __restrict__ bf0c, bf16* __restrict__ h0,
               float* __restrict__ c0)
{
    int idx = blockIdx.x * 256 + threadIdx.x;     // = r*512 + hu
    int r = idx >> 9, hu = idx & 511;
    const float* xr = x + (size_t)r * (TSTEPS * FINP);
    f32x4 xv0 = *(const f32x4*)xr;
    f32x4 xv1 = *(const f32x4*)(xr + 4);
    int jb = ((hu >> 4) << 6) + (hu & 15);
    float g[4];
#pragma unroll
    for (int gg = 0; gg < 4; ++gg) {
        const float* wrow = Wf0c + (size_t)(jb + gg * 16) * 8;
        f32x4 w0 = *(const f32x4*)wrow;
        f32x4 w1 = *(const f32x4*)(wrow + 4);
        f32x4 p = xv0 * w0 + xv1 * w1;
        g[gg] = bf0c[jb + gg * 16] + p[0] + p[1] + p[2] + p[3];
    }
    float iv = sigf(g[0]), gv = tanhf_(g[2]), ov = sigf(g[3]);
    float cn = iv * gv;                            // c_prev = 0
    c0[idx] = cn;
    h0[idx] = (bf16)(ov * tanhf_(cn));
}

// ---------------------------------------------------------------------------
// fc1: Z = A @ W^T + b (fp32 out). grid (32,4).
// ---------------------------------------------------------------------------
__global__ __launch_bounds__(256)
void fc1_mfma(const bf16* __restrict__ A, const bf16* __restrict__ W,
              const float* __restrict__ bias, float* __restrict__ Z)
{
    __shared__ __align__(16) bf16 As[2][4096], Ws[2][4096];
    int nwg  = (int)(gridDim.x * gridDim.y);
    int orig = (int)(blockIdx.x + blockIdx.y * gridDim.x);
    int swz  = (orig & 7) * (nwg >> 3) + (orig >> 3);
    const int m0 = (swz & 31) * 128, n0 = (swz >> 5) * 128;
    f32x4 acc[4][4];
#pragma unroll
    for (int m = 0; m < 4; ++m)
#pragma unroll
        for (int n = 0; n < 4; ++n) acc[m][n] = (f32x4){0.f, 0.f, 0.f, 0.f};
    gemm_acc(A, W, nullptr, nullptr, 1, m0, n0, As, Ws, acc);

    const int tid = threadIdx.x, lane = tid & 63, w = tid >> 6;
    const int wr = w >> 1, wc = w & 1, l16 = lane & 15, lq = lane >> 4;
#pragma unroll
    for (int m = 0; m < 4; ++m) {
        const int rb = m0 + wr * 64 + m * 16 + lq * 4;
#pragma unroll
        for (int n = 0; n < 4; ++n) {
            const int col = n0 + wc * 64 + n * 16 + l16;
            float bv = bias[col];
#pragma unroll
            for (int q = 0; q < 4; ++q)
                Z[(size_t)(rb + q) * HID + col] = acc[m][n][q] + bv;
        }
    }
}

// ---------------------------------------------------------------------------
// LayerNorm + ReLU + fc2 (8 outs), one wave per row.
// ---------------------------------------------------------------------------
__global__ __launch_bounds__(256)
void ln_fc2_kernel(const float* __restrict__ Z, const float* __restrict__ lng,
                   const float* __restrict__ lnb, const float* __restrict__ w2,
                   const float* __restrict__ b2, float* __restrict__ out)
{
    int wave = threadIdx.x >> 6;
    int lane = threadIdx.x & 63;
    int n = blockIdx.x * 4 + wave;
    const float* zr = Z + (size_t)n * HID;

    float v[8];
    float s1 = 0.f, s2 = 0.f;
#pragma unroll
    for (int j = 0; j < 8; ++j) {
        v[j] = zr[lane + j * 64];
        s1 += v[j];
        s2 += v[j] * v[j];
    }
#pragma unroll
    for (int off = 32; off; off >>= 1) {
        s1 += __shfl_down(s1, off);
        s2 += __shfl_down(s2, off);
    }
    s1 = __shfl(s1, 0);
    s2 = __shfl(s2, 0);
    float mu = s1 * (1.f / 512.f);
    float var = s2 * (1.f / 512.f) - mu * mu;
    float rs = rsqrtf(var + 1e-5f);

    float y[8];
#pragma unroll
    for (int f = 0; f < 8; ++f) y[f] = 0.f;
#pragma unroll
    for (int j = 0; j < 8; ++j) {
        int h = lane + j * 64;
        float zn = (v[j] - mu) * rs * lng[h] + lnb[h];
        zn = fmaxf(zn, 0.f);
#pragma unroll
        for (int f = 0; f < 8; ++f) y[f] += zn * w2[f * HID + h];
    }
#pragma unroll
    for (int f = 0; f < 8; ++f)
#pragma unroll
        for (int off = 32; off; off >>= 1) y[f] += __shfl_down(y[f], off);

    if (lane == 0) {
#pragma unroll
        for (int f = 0; f < 8; ++f) out[(size_t)n * 256 + f] = y[f] + b2[f];
    }
}

// ---------------------------------------------------------------------------
// Weight preprocessing
// ---------------------------------------------------------------------------
__device__ __forceinline__ int remap_j(int j) {
    int gate = j >> 9, hu = j & 511;
    return ((hu >> 4) << 6) + (gate << 4) + (hu & 15);
}

__global__ void fold_small(const float* __restrict__ Wih0, const float* __restrict__ We,
                           const float* __restrict__ be, const float* __restrict__ bih0,
                           const float* __restrict__ bhh0, const float* __restrict__ bih1,
                           const float* __restrict__ bhh1,
                           float* __restrict__ Wf0c, float* __restrict__ bf0c,
                           float* __restrict__ bs1c)
{
    int j = blockIdx.x * 256 + threadIdx.x;
    if (j >= G4H) return;
    int jn = remap_j(j);
    float acc[FINP];
#pragma unroll
    for (int f = 0; f < FINP; ++f) acc[f] = 0.f;
    float bacc = 0.f;
    for (int e = 0; e < EDIM; ++e) {
        float wv = Wih0[(size_t)j * EDIM + e];
        bacc += wv * be[e];
#pragma unroll
        for (int f = 0; f < FINP; ++f) acc[f] += wv * We[e * FINP + f];
    }
#pragma unroll
    for (int f = 0; f < FINP; ++f) Wf0c[(size_t)jn * FINP + f] = acc[f];
    bf0c[jn] = bacc + bih0[j] + bhh0[j];
    bs1c[jn] = bih1[j] + bhh1[j];
}

__global__ void conv_w(const float* __restrict__ W0, const float* __restrict__ W1,
                       const float* __restrict__ W2,
                       bf16* __restrict__ O0, bf16* __restrict__ O1, bf16* __restrict__ O2)
{
    int j = blockIdx.x;
    int which = blockIdx.y;
    const float* src = which == 0 ? W0 : which == 1 ? W1 : W2;
    bf16* dst = which == 0 ? O0 : which == 1 ? O1 : O2;
    int jn = remap_j(j);
    for (int k = threadIdx.x; k < HID; k += 256)
        dst[(size_t)jn * HID + k] = (bf16)src[(size_t)j * HID + k];
}

__global__ void conv_fc1(const float* __restrict__ W, bf16* __restrict__ O)
{
    int j = blockIdx.x;
    for (int k = threadIdx.x; k < HID; k += 256)
        O[(size_t)j * HID + k] = (bf16)W[(size_t)j * HID + k];
}

// ---------------------------------------------------------------------------
extern "C" void kernel_launch(void* const* d_in, const int* in_sizes, int n_in,
                              void* d_out, int out_size, void* d_ws, size_t ws_size,
                              hipStream_t stream)
{
    const float* x    = (const float*)d_in[0];
    const float* We   = (const float*)d_in[1];
    const float* be   = (const float*)d_in[2];
    const float* Wih0 = (const float*)d_in[3];
    const float* Whh0 = (const float*)d_in[4];
    const float* bih0 = (const float*)d_in[5];
    const float* bhh0 = (const float*)d_in[6];
    const float* Wih1 = (const float*)d_in[7];
    const float* Whh1 = (const float*)d_in[8];
    const float* bih1 = (const float*)d_in[9];
    const float* bhh1 = (const float*)d_in[10];
    const float* fc1w = (const float*)d_in[11];
    const float* fc1b = (const float*)d_in[12];
    const float* lng  = (const float*)d_in[13];
    const float* lnb  = (const float*)d_in[14];
    const float* fc2w = (const float*)d_in[15];
    const float* fc2b = (const float*)d_in[16];
    float* out = (float*)d_out;

    char* p = (char*)d_ws;
    auto alloc = [&](size_t bytes) -> void* {
        void* r = (void*)p;
        p += (bytes + 255) & ~(size_t)255;
        return r;
    };
    bf16*  Whh0c = (bf16*)alloc((size_t)G4H * HID * 2);
    bf16*  Wih1c = (bf16*)alloc((size_t)G4H * HID * 2);
    bf16*  Whh1c = (bf16*)alloc((size_t)G4H * HID * 2);
    bf16*  fc1wb = (bf16*)alloc((size_t)HID * HID * 2);
    float* Wf0c  = (float*)alloc((size_t)G4H * FINP * 4);
    float* bf0c  = (float*)alloc((size_t)G4H * 4);
    float* bs1c  = (float*)alloc((size_t)G4H * 4);
    const size_t S = (size_t)NB * HID;
    bf16*  H0[2]; H0[0] = (bf16*)alloc(S * 2); H0[1] = (bf16*)alloc(S * 2);
    bf16*  H1[2]; H1[0] = (bf16*)alloc(S * 2); H1[1] = (bf16*)alloc(S * 2);
    float* c0    = (float*)alloc(S * 4);
    float* c1    = (float*)alloc(S * 4);
    float* Z     = (float*)alloc(S * 4);

    hipMemsetAsync(c1, 0, S * 4, stream);   // layer1[0] epilogue reads c1

    fold_small<<<8, 256, 0, stream>>>(Wih0, We, be, bih0, bhh0, bih1, bhh1, Wf0c, bf0c, bs1c);
    conv_w<<<dim3(G4H, 3), 256, 0, stream>>>(Whh0, Wih1, Whh1, Whh0c, Wih1c, Whh1c);
    conv_fc1<<<HID, 256, 0, stream>>>(fc1w, fc1wb);

    // ----- encoder: t = 0..62 (63 steps). h0[t] in H0[t&1], h1[t] in H1[t&1].
    init_step<<<NB * HID / 256, 256, 0, stream>>>(x, Wf0c, bf0c, H0[0], c0);

    dim3 fg(32, 32), lb(256);
    for (int t = 0; t < TSTEPS - 2; ++t) {   // t = 0..61: layer0[t+1] || layer1[t]
        if (t == 0)
            enc_fused<false><<<fg, lb, 0, stream>>>(H0[0], Whh0c, Wf0c, bf0c,
                x + (size_t)1 * FINP, H0[1], c0,
                Wih1c, nullptr, Whh1c, bs1c, H1[0], c1);
        else
            enc_fused<true><<<fg, lb, 0, stream>>>(H0[t & 1], Whh0c, Wf0c, bf0c,
                x + (size_t)(t + 1) * FINP, H0[(t + 1) & 1], c0,
                Wih1c, H1[(t + 1) & 1], Whh1c, bs1c, H1[t & 1], c1);
    }
    // final layer1[62]: reads h0[62]=H0[0], h1[61]=H1[1], writes H1[0]
    lstm_step<2, false><<<dim3(32, 16), lb, 0, stream>>>(
        H0[0], Wih1c, H1[1], Whh1c, nullptr, bs1c, nullptr, 0, c1, H1[0]);

    // ----- decoder: s = 0..31.
    for (int s = 0; s < FWIN; ++s) {
        const float* xA = (s == 0) ? (x + (size_t)(TSTEPS - 1) * FINP)
                                   : (out + (size_t)(s - 1) * FINP);
        int sx = (s == 0) ? (TSTEPS * FINP) : (FWIN * FINP);
        lstm_step<1, true><<<dim3(32, 16), lb, 0, stream>>>(
            H0[s & 1], Whh0c, nullptr, nullptr, Wf0c, bf0c, xA, sx, c0, H0[(s + 1) & 1]);
        lstm_step<2, false><<<dim3(32, 16), lb, 0, stream>>>(
            H0[(s + 1) & 1], Wih1c, H1[s & 1], Whh1c, nullptr, bs1c, nullptr, 0,
            c1, H1[(s + 1) & 1]);
        fc1_mfma<<<dim3(32, 4), lb, 0, stream>>>(H1[(s + 1) & 1], fc1wb, fc1b, Z);
        ln_fc2_kernel<<<NB / 4, 256, 0, stream>>>(Z, lng, lnb, fc2w, fc2b,
                                                  out + (size_t)s * FINP);
    }
}